// Round 4
// baseline (530.037 us; speedup 1.0000x reference)
//
#include <hip/hip_runtime.h>
#include <math.h>

// ---------------- workspace layout (float offsets) ----------------
static constexpr int OFF_BAS = 0;            // 1176: basis [tz][ty][r][8]
static constexpr int OFF_W   = 1280;         // 36128: folded weights (rows padded to K4)
static constexpr int OFF_ACC = 37504;        // 256: chsum[5][48] @0, insum @240
static constexpr int OFF_XA  = 37888;        // 761856: xcat ping  (max 2*93*4096)
static constexpr int OFF_XB  = OFF_XA + 761856;
static constexpr int OFF_U   = OFF_XB + 761856;  // 1105920 (max 2*135*4096)
static constexpr int OFF_Y   = OFF_U + 1105920;  // 368640  (max 2*45*4096)

// W sub-offsets (padded M rows: 24,72,136,136,136,8 ; K padded to K4: 16,40,44,96,96,96)
static constexpr int WOFF0 = OFF_W + 0;      // 24x16
static constexpr int WOFF1 = OFF_W + 384;    // 72x40
static constexpr int WOFF2 = OFF_W + 3264;   // 136x44
static constexpr int WOFF3 = OFF_W + 9248;   // 136x96
static constexpr int WOFF4 = OFF_W + 22304;  // 136x96
static constexpr int WOFF5 = OFF_W + 35360;  // 8x96

__device__ __forceinline__ float wred(float s) {
  #pragma unroll
  for (int o = 32; o > 0; o >>= 1) s += __shfl_xor(s, o, 64);
  return s;
}

// ---------------- prep: basis init + weight fold (TP symmetry compressed) ----------------
__global__ __launch_bounds__(128) void prep_kernel(
    const float* __restrict__ w0, const float* __restrict__ w1,
    const float* __restrict__ w2, const float* __restrict__ w3,
    const float* __restrict__ w4, const float* __restrict__ w5,
    float* __restrict__ ws) {
  const int blk = blockIdx.x;
  const int tid = threadIdx.x;
  if (blk == 0) {
    // basis[tz][ty][r][8] : exp(-(dist - 1.5 r)^2 / 4.5), tx==7 slot zero-padded
    for (int i = tid; i < 1176; i += 128) {
      int tx = i & 7;
      int r  = (i >> 3) % 3;
      int ty = (i / 24) % 7;
      int tz = i / 168;
      float val = 0.f;
      if (tx < 7) {
        double dx = tx - 3, dy = ty - 3, dz = tz - 3;
        double dist = sqrt(dx * dx + dy * dy + dz * dz);
        double d = dist - 1.5 * (double)r;
        val = (float)exp(-(d * d) / 4.5);
      }
      ws[OFF_BAS + i] = val;
    }
    return;
  }
  const int row = blk - 1;  // 0..511
  const int rs[6]    = {0, 24, 96, 232, 368, 504};
  const int kk[6]    = {15, 37, 42, 93, 93, 93};
  const int k4[6]    = {16, 40, 44, 96, 96, 96};
  const int coutt[6] = {19, 24, 45, 45, 45, 1};
  const int cinf[6]  = {5, 46, 51, 117, 117, 117};
  const int chin_[6] = {5, 19, 24, 45, 45, 45};
  const int woff[6]  = {WOFF0, WOFF1, WOFF2, WOFF3, WOFF4, WOFF5};
  const float* wptr[6] = {w0, w1, w2, w3, w4, w5};
  int l = 0;
  while (l < 5 && row >= rs[l + 1]) ++l;
  const int m = row - rs[l];
  const int K = kk[l], K4 = k4[l];
  const float* w = wptr[l];
  float* Wo = ws + woff[l] + m * K4;
  if (l == 0) {
    // layer 0 is depthwise-first: W[o][c*3+r], cout=19, cin(dw)=15
    for (int k = tid; k < 16; k += 128) {
      float v = 0.f;
      if (m < 19 && k < 15) { int c = k / 3, r = k % 3; v = w[(m * 5 + c) * 3 + r]; }
      Wo[k] = v;
    }
    return;
  }
  const int o = m / 3, r = m % 3;
  const int cout = coutt[l];
  const int cf = cinf[l], ch = chin_[l];
  const int itab[6] = {0, 0, 0, 1, 1, 2};
  const int jtab[6] = {0, 1, 2, 1, 2, 2};
  for (int k = tid; k < K4; k += 128) {
    float v = 0.f;
    if (o < cout && k < K) {
      if (k < ch) {
        v = w[(o * cf + k) * 3 + r];
      } else {
        int cc = k - ch;
        int mm = cc / 6, uu = cc % 6;
        int i = itab[uu], j = jtab[uu];
        v = w[(o * cf + ch + mm * 9 + i * 3 + j) * 3 + r];
        if (i != j) v += w[(o * cf + ch + mm * 9 + j * 3 + i) * 3 + r];
      }
    }
    Wo[k] = v;
  }
}

// ---------------- input channel sums (for the skip linear term) ----------------
__global__ __launch_bounds__(256) void insum_kernel(const float* __restrict__ x,
                                                    float* __restrict__ insum) {
  const int g = blockIdx.x * 256 + threadIdx.x;  // 81920 float4
  float4 v = ((const float4*)x)[g];
  float s = v.x + v.y + v.z + v.w;
  s = wred(s);
  if ((threadIdx.x & 63) == 0) atomicAdd(&insum[g >> 13], s);
}

// ---------------- layer 0: stride-2 depthwise (5 ch, 32^3 -> 16^3, 3 radial) ----------------
__global__ __launch_bounds__(256) void dw0_kernel(const float* __restrict__ x,
                                                  const float* __restrict__ basg,
                                                  float* __restrict__ z0) {
  const int g = blockIdx.x * 256 + threadIdx.x;  // 40960
  const int p = g & 4095;
  const int c = (g >> 12) % 5;
  const int b = g / (5 * 4096);
  const int X = p & 15, Y = (p >> 4) & 15, Z = p >> 8;
  const float* xp = x + (((size_t)(b * 5 + c)) << 15);
  float a0 = 0.f, a1 = 0.f, a2 = 0.f;
  for (int tz = 0; tz < 7; ++tz) {
    const int iz = 2 * Z + tz - 3;
    if ((unsigned)iz >= 32u) continue;
    for (int ty = 0; ty < 7; ++ty) {
      const int iy = 2 * Y + ty - 3;
      if ((unsigned)iy >= 32u) continue;
      const float* bb = &basg[(tz * 7 + ty) * 24];
      const float* row = xp + (iz << 10) + (iy << 5);
      #pragma unroll
      for (int tx = 0; tx < 7; ++tx) {
        const int ix = 2 * X + tx - 3;
        float v = ((unsigned)ix < 32u) ? row[ix] : 0.f;
        a0 = fmaf(bb[tx], v, a0);
        a1 = fmaf(bb[8 + tx], v, a1);
        a2 = fmaf(bb[16 + tx], v, a2);
      }
    }
  }
  const size_t base = (((size_t)(b * 15 + c * 3)) << 12) + p;
  z0[base] = a0;
  z0[base + 4096] = a1;
  z0[base + 8192] = a2;
}

// ---------------- GEMM: out[b,m,p] = sum_k W[m,k] * in[b,k,p]  (+ optional per-ch sumsq) ----
// W rows padded to K4, staged in LDS; each thread: 4 spatial (float4) x 8 channels
template <int K>
__global__ __launch_bounds__(256) void gemm_kernel(
    const float* __restrict__ in, const float* __restrict__ W,
    float* __restrict__ out, int Mreal, float* __restrict__ chsum) {
  constexpr int K4 = (K + 3) & ~3;
  __shared__ float Wl[8 * K4];
  const int b = blockIdx.z;
  const int m0 = blockIdx.y * 8;
  const int p0 = blockIdx.x * 1024 + threadIdx.x * 4;
  for (int i = threadIdx.x; i < 8 * K4; i += 256) Wl[i] = W[m0 * K4 + i];
  __syncthreads();
  const float* ip = in + (((size_t)b * K) << 12) + p0;
  float4 acc[8];
  #pragma unroll
  for (int j = 0; j < 8; ++j) acc[j] = make_float4(0.f, 0.f, 0.f, 0.f);
  int k = 0;
  for (; k + 4 <= K; k += 4) {
    const float4 v0 = *(const float4*)&ip[(size_t)(k + 0) << 12];
    const float4 v1 = *(const float4*)&ip[(size_t)(k + 1) << 12];
    const float4 v2 = *(const float4*)&ip[(size_t)(k + 2) << 12];
    const float4 v3 = *(const float4*)&ip[(size_t)(k + 3) << 12];
    #pragma unroll
    for (int j = 0; j < 8; ++j) {
      const float4 wv = *(const float4*)&Wl[j * K4 + k];
      acc[j].x = fmaf(wv.x, v0.x, acc[j].x); acc[j].y = fmaf(wv.x, v0.y, acc[j].y);
      acc[j].z = fmaf(wv.x, v0.z, acc[j].z); acc[j].w = fmaf(wv.x, v0.w, acc[j].w);
      acc[j].x = fmaf(wv.y, v1.x, acc[j].x); acc[j].y = fmaf(wv.y, v1.y, acc[j].y);
      acc[j].z = fmaf(wv.y, v1.z, acc[j].z); acc[j].w = fmaf(wv.y, v1.w, acc[j].w);
      acc[j].x = fmaf(wv.z, v2.x, acc[j].x); acc[j].y = fmaf(wv.z, v2.y, acc[j].y);
      acc[j].z = fmaf(wv.z, v2.z, acc[j].z); acc[j].w = fmaf(wv.z, v2.w, acc[j].w);
      acc[j].x = fmaf(wv.w, v3.x, acc[j].x); acc[j].y = fmaf(wv.w, v3.y, acc[j].y);
      acc[j].z = fmaf(wv.w, v3.z, acc[j].z); acc[j].w = fmaf(wv.w, v3.w, acc[j].w);
    }
  }
  for (; k < K; ++k) {
    const float4 v = *(const float4*)&ip[(size_t)k << 12];
    #pragma unroll
    for (int j = 0; j < 8; ++j) {
      const float w = Wl[j * K4 + k];
      acc[j].x = fmaf(w, v.x, acc[j].x); acc[j].y = fmaf(w, v.y, acc[j].y);
      acc[j].z = fmaf(w, v.z, acc[j].z); acc[j].w = fmaf(w, v.w, acc[j].w);
    }
  }
  #pragma unroll
  for (int j = 0; j < 8; ++j) {
    const int m = m0 + j;
    if (m < Mreal) *(float4*)&out[(((size_t)(b * Mreal + m)) << 12) + p0] = acc[j];
  }
  if (chsum) {
    #pragma unroll
    for (int j = 0; j < 8; ++j) {
      float s = acc[j].x * acc[j].x + acc[j].y * acc[j].y +
                acc[j].z * acc[j].z + acc[j].w * acc[j].w;
      s = wred(s);
      if ((threadIdx.x & 63) == 0) atomicAdd(&chsum[m0 + j], s);
    }
  }
}

// ---------------- depthwise-last: y[b,o,p] = sum_r basis_r (x) u[b,o*3+r,p] ----------------
// block: (zslab 0..3, o) x b ; threads 256 = (bx:4, y:16, zz:4); each thread 4 x-outputs
__global__ __launch_bounds__(256) void dwB_kernel(
    const float* __restrict__ u, const float* __restrict__ basg,
    float* __restrict__ y, float* __restrict__ chsum, int cout) {
  __shared__ float lin[15840];  // [3 ch][10 z][22 y][24 x], x base = -4
  const int b = blockIdx.y;
  const int o = blockIdx.x >> 2;
  const int zs = blockIdx.x & 3;
  const int tid = threadIdx.x;
  const int z0 = zs * 4;
  const float* ubase = u + (((size_t)(b * 3 * cout + o * 3)) << 12);
  for (int i = tid; i < 15840; i += 256) {
    const int dx = i % 24;
    int t = i / 24;
    const int dy = t % 22;
    t /= 22;
    const int dz = t % 10;
    const int ch = t / 10;
    const int gz = z0 + dz - 3, gy = dy - 3, gx = dx - 4;
    float v = 0.f;
    if ((unsigned)gz < 16u && (unsigned)gy < 16u && (unsigned)gx < 16u)
      v = ubase[(ch << 12) + (gz << 8) + (gy << 4) + gx];
    lin[i] = v;
  }
  __syncthreads();
  const int bx = tid & 3, yy = (tid >> 2) & 15, zz = tid >> 6;
  float acc[4] = {0.f, 0.f, 0.f, 0.f};
  #pragma unroll 1
  for (int tz = 0; tz < 7; ++tz) {
    #pragma unroll 1
    for (int ty = 0; ty < 7; ++ty) {
      const int rb = ((zz + tz) * 22 + (yy + ty)) * 24 + bx * 4;
      float4 a0 = *(const float4*)&lin[rb];
      float4 a1 = *(const float4*)&lin[rb + 4];
      float4 a2 = *(const float4*)&lin[rb + 8];
      float4 b0 = *(const float4*)&lin[rb + 5280];
      float4 b1 = *(const float4*)&lin[rb + 5284];
      float4 b2 = *(const float4*)&lin[rb + 5288];
      float4 c0 = *(const float4*)&lin[rb + 10560];
      float4 c1 = *(const float4*)&lin[rb + 10564];
      float4 c2 = *(const float4*)&lin[rb + 10568];
      const float* bb = &basg[(tz * 7 + ty) * 24];
      const float va[12] = {a0.x,a0.y,a0.z,a0.w,a1.x,a1.y,a1.z,a1.w,a2.x,a2.y,a2.z,a2.w};
      const float vb[12] = {b0.x,b0.y,b0.z,b0.w,b1.x,b1.y,b1.z,b1.w,b2.x,b2.y,b2.z,b2.w};
      const float vc[12] = {c0.x,c0.y,c0.z,c0.w,c1.x,c1.y,c1.z,c1.w,c2.x,c2.y,c2.z,c2.w};
      #pragma unroll
      for (int tx = 0; tx < 7; ++tx) {
        const float w0 = bb[tx], w1 = bb[8 + tx], w2 = bb[16 + tx];
        #pragma unroll
        for (int i2 = 0; i2 < 4; ++i2) {
          acc[i2] = fmaf(w0, va[i2 + tx + 1], acc[i2]);
          acc[i2] = fmaf(w1, vb[i2 + tx + 1], acc[i2]);
          acc[i2] = fmaf(w2, vc[i2 + tx + 1], acc[i2]);
        }
      }
    }
  }
  const int p = ((z0 + zz) << 8) + (yy << 4) + bx * 4;
  float4 outv = {acc[0], acc[1], acc[2], acc[3]};
  *(float4*)&y[(((size_t)(b * cout + o)) << 12) + p] = outv;
  if (chsum) {
    float s = acc[0]*acc[0] + acc[1]*acc[1] + acc[2]*acc[2] + acc[3]*acc[3];
    s = wred(s);
    if ((tid & 63) == 0) atomicAdd(&chsum[o], s);
  }
}

// ---------------- norm + bias/relu + compressed TensorProduct -> next xcat ----------------
template <int COUT, int N1, int N3>
__global__ __launch_bounds__(64) void post_kernel(
    const float* __restrict__ y, const float* __restrict__ chsum,
    const float* __restrict__ bias, float* __restrict__ xout) {
  constexpr int N5 = (COUT - N1 - 3 * N3) / 5;
  constexpr int CO = COUT + 6 * N3;
  const int b = blockIdx.y;
  const int p = blockIdx.x * 64 + threadIdx.x;
  const float* yp = y + (((size_t)b * COUT) << 12) + p;
  float* xp = xout + (((size_t)b * CO) << 12) + p;
  const float inv = 1.f / 8192.f;
  float vals[COUT];
  #pragma unroll
  for (int c = 0; c < N1; ++c) {
    const float f = 1.f / sqrtf(chsum[c] * inv + 1e-5f);
    const float v = yp[(size_t)c << 12] * f + bias[c];
    vals[c] = v > 0.f ? v : 0.f;
  }
  #pragma unroll
  for (int m = 0; m < N3; ++m) {
    const int c0 = N1 + 3 * m;
    const float f = 1.f / sqrtf((chsum[c0] + chsum[c0 + 1] + chsum[c0 + 2]) * inv + 1e-5f);
    vals[c0]     = yp[(size_t)c0 << 12] * f;
    vals[c0 + 1] = yp[(size_t)(c0 + 1) << 12] * f;
    vals[c0 + 2] = yp[(size_t)(c0 + 2) << 12] * f;
  }
  #pragma unroll
  for (int m = 0; m < N5; ++m) {
    const int c0 = N1 + 3 * N3 + 5 * m;
    const float s5 = chsum[c0] + chsum[c0+1] + chsum[c0+2] + chsum[c0+3] + chsum[c0+4];
    const float f = 1.f / sqrtf(s5 * inv + 1e-5f);
    #pragma unroll
    for (int d = 0; d < 5; ++d) vals[c0 + d] = yp[(size_t)(c0 + d) << 12] * f;
  }
  #pragma unroll
  for (int c = 0; c < COUT; ++c) xp[(size_t)c << 12] = vals[c];
  #pragma unroll
  for (int m = 0; m < N3; ++m) {
    const float v0 = vals[N1 + 3*m], v1 = vals[N1 + 3*m + 1], v2 = vals[N1 + 3*m + 2];
    const float t[6] = {v0*v0, v0*v1, v0*v2, v1*v1, v1*v2, v2*v2};
    #pragma unroll
    for (int uu = 0; uu < 6; ++uu) xp[(size_t)(COUT + m * 6 + uu) << 12] = t[uu];
  }
}

// ---------------- final: spatial mean of y5 + input-sum linear term ----------------
__global__ __launch_bounds__(256) void final_kernel(
    const float* __restrict__ y5, const float* __restrict__ acc,
    const float* __restrict__ lin_w, const float* __restrict__ lin_b,
    const float* __restrict__ alpha, float* __restrict__ out) {
  const int b = blockIdx.x;
  const int tid = threadIdx.x;
  float s = 0.f;
  for (int i = tid; i < 4096; i += 256) s += y5[(b << 12) + i];
  s = wred(s);
  __shared__ float ls[4];
  if ((tid & 63) == 0) ls[tid >> 6] = s;
  __syncthreads();
  if (tid == 0) {
    const float t = ls[0] + ls[1] + ls[2] + ls[3];
    float res = t * (1.f / 4096.f) * alpha[0] * 0.1f;
    const float* insum = acc + 240;
    for (int c = 0; c < 5; ++c) res += insum[b * 5 + c] * lin_w[c];
    res += lin_b[0];
    out[b] = res;
  }
}

extern "C" void kernel_launch(void* const* d_in, const int* in_sizes, int n_in,
                              void* d_out, int out_size, void* d_ws, size_t ws_size,
                              hipStream_t stream) {
  const float* x  = (const float*)d_in[0];
  const float* w0 = (const float*)d_in[1];
  const float* w1 = (const float*)d_in[2];
  const float* w2 = (const float*)d_in[3];
  const float* w3 = (const float*)d_in[4];
  const float* w4 = (const float*)d_in[5];
  const float* w5 = (const float*)d_in[6];
  const float* b0 = (const float*)d_in[7];
  const float* b1 = (const float*)d_in[8];
  const float* b2 = (const float*)d_in[9];
  const float* b3 = (const float*)d_in[10];
  const float* b4 = (const float*)d_in[11];
  const float* lw = (const float*)d_in[12];
  const float* lb = (const float*)d_in[13];
  const float* al = (const float*)d_in[14];
  float* out = (float*)d_out;
  float* ws = (float*)d_ws;

  float* bas = ws + OFF_BAS;
  float* acc = ws + OFF_ACC;
  float* XA = ws + OFF_XA;
  float* XB = ws + OFF_XB;
  float* U  = ws + OFF_U;
  float* Y  = ws + OFF_Y;

  hipMemsetAsync(acc, 0, 256 * sizeof(float), stream);
  hipLaunchKernelGGL(prep_kernel, dim3(513), dim3(128), 0, stream, w0, w1, w2, w3, w4, w5, ws);
  hipLaunchKernelGGL(insum_kernel, dim3(320), dim3(256), 0, stream, x, acc + 240);

  // L0: depthwise-first (stride 2), then GEMM (+sumsq), then norm/relu + TP -> XA (37 ch)
  hipLaunchKernelGGL(dw0_kernel, dim3(160), dim3(256), 0, stream, x, bas, U);
  hipLaunchKernelGGL(gemm_kernel<15>, dim3(4, 3, 2), dim3(256), 0, stream,
                     U, ws + WOFF0, Y, 19, acc);
  hipLaunchKernelGGL((post_kernel<19, 10, 3>), dim3(64, 2), dim3(64), 0, stream, Y, acc, b0, XA);

  // L1: GEMM-first (K=37 -> 72 u-ch), depthwise(+sumsq), post -> XB (42 ch)
  hipLaunchKernelGGL(gemm_kernel<37>, dim3(4, 9, 2), dim3(256), 0, stream,
                     XA, ws + WOFF1, U, 72, (float*)nullptr);
  hipLaunchKernelGGL(dwB_kernel, dim3(96, 2), dim3(256), 0, stream, U, bas, Y, acc + 48, 24);
  hipLaunchKernelGGL((post_kernel<24, 10, 3>), dim3(64, 2), dim3(64), 0, stream, Y, acc + 48, b1, XB);

  // L2: K=42 -> 135 u-ch, cout=45 -> XA (93 ch)
  hipLaunchKernelGGL(gemm_kernel<42>, dim3(4, 17, 2), dim3(256), 0, stream,
                     XB, ws + WOFF2, U, 135, (float*)nullptr);
  hipLaunchKernelGGL(dwB_kernel, dim3(180, 2), dim3(256), 0, stream, U, bas, Y, acc + 96, 45);
  hipLaunchKernelGGL((post_kernel<45, 16, 8>), dim3(64, 2), dim3(64), 0, stream, Y, acc + 96, b2, XA);

  // L3
  hipLaunchKernelGGL(gemm_kernel<93>, dim3(4, 17, 2), dim3(256), 0, stream,
                     XA, ws + WOFF3, U, 135, (float*)nullptr);
  hipLaunchKernelGGL(dwB_kernel, dim3(180, 2), dim3(256), 0, stream, U, bas, Y, acc + 144, 45);
  hipLaunchKernelGGL((post_kernel<45, 16, 8>), dim3(64, 2), dim3(64), 0, stream, Y, acc + 144, b3, XB);

  // L4
  hipLaunchKernelGGL(gemm_kernel<93>, dim3(4, 17, 2), dim3(256), 0, stream,
                     XB, ws + WOFF4, U, 135, (float*)nullptr);
  hipLaunchKernelGGL(dwB_kernel, dim3(180, 2), dim3(256), 0, stream, U, bas, Y, acc + 192, 45);
  hipLaunchKernelGGL((post_kernel<45, 16, 8>), dim3(64, 2), dim3(64), 0, stream, Y, acc + 192, b4, XA);

  // L5: cout=1, no norm
  hipLaunchKernelGGL(gemm_kernel<93>, dim3(4, 1, 2), dim3(256), 0, stream,
                     XA, ws + WOFF5, U, 3, (float*)nullptr);
  hipLaunchKernelGGL(dwB_kernel, dim3(4, 2), dim3(256), 0, stream, U, bas, Y, (float*)nullptr, 1);

  hipLaunchKernelGGL(final_kernel, dim3(2), dim3(256), 0, stream, Y, acc, lw, lb, al, out);
}

// Round 5
// 443.148 us; speedup vs baseline: 1.1961x; 1.1961x over previous
//
#include <hip/hip_runtime.h>
#include <math.h>

// ---------------- workspace layout (float offsets) ----------------
static constexpr int OFF_BAS = 0;            // 1176: basis [tz][ty][r][8]
static constexpr int OFF_W   = 1280;         // 36128: folded weights (rows padded to K4)
static constexpr int OFF_ACC = 37504;        // 256: chsum[5][48] @0, insum @240
static constexpr int OFF_XA  = 37888;        // 761856: xcat ping  (max 2*93*4096)
static constexpr int OFF_XB  = OFF_XA + 761856;
static constexpr int OFF_U   = OFF_XB + 761856;  // 1105920 (max 2*135*4096)
static constexpr int OFF_Y   = OFF_U + 1105920;  // 368640  (max 2*45*4096)

// W sub-offsets (padded M rows: 24,72,136,136,136,8 ; K padded to K4: 16,40,44,96,96,96)
static constexpr int WOFF0 = OFF_W + 0;      // 24x16
static constexpr int WOFF1 = OFF_W + 384;    // 72x40
static constexpr int WOFF2 = OFF_W + 3264;   // 136x44
static constexpr int WOFF3 = OFF_W + 9248;   // 136x96
static constexpr int WOFF4 = OFF_W + 22304;  // 136x96
static constexpr int WOFF5 = OFF_W + 35360;  // 8x96

__device__ __forceinline__ float wred(float s) {
  #pragma unroll
  for (int o = 32; o > 0; o >>= 1) s += __shfl_xor(s, o, 64);
  return s;
}

// ---------------- prep: basis init + weight fold (TP symmetry compressed) ----------------
__global__ __launch_bounds__(128) void prep_kernel(
    const float* __restrict__ w0, const float* __restrict__ w1,
    const float* __restrict__ w2, const float* __restrict__ w3,
    const float* __restrict__ w4, const float* __restrict__ w5,
    float* __restrict__ ws) {
  const int blk = blockIdx.x;
  const int tid = threadIdx.x;
  if (blk == 0) {
    // basis[tz][ty][r][8] : exp(-(dist - 1.5 r)^2 / 4.5), tx==7 slot zero-padded
    for (int i = tid; i < 1176; i += 128) {
      int tx = i & 7;
      int r  = (i >> 3) % 3;
      int ty = (i / 24) % 7;
      int tz = i / 168;
      float val = 0.f;
      if (tx < 7) {
        double dx = tx - 3, dy = ty - 3, dz = tz - 3;
        double dist = sqrt(dx * dx + dy * dy + dz * dz);
        double d = dist - 1.5 * (double)r;
        val = (float)exp(-(d * d) / 4.5);
      }
      ws[OFF_BAS + i] = val;
    }
    return;
  }
  const int row = blk - 1;  // 0..511
  const int rs[6]    = {0, 24, 96, 232, 368, 504};
  const int kk[6]    = {15, 37, 42, 93, 93, 93};
  const int k4[6]    = {16, 40, 44, 96, 96, 96};
  const int coutt[6] = {19, 24, 45, 45, 45, 1};
  const int cinf[6]  = {5, 46, 51, 117, 117, 117};
  const int chin_[6] = {5, 19, 24, 45, 45, 45};
  const int woff[6]  = {WOFF0, WOFF1, WOFF2, WOFF3, WOFF4, WOFF5};
  const float* wptr[6] = {w0, w1, w2, w3, w4, w5};
  int l = 0;
  while (l < 5 && row >= rs[l + 1]) ++l;
  const int m = row - rs[l];
  const int K = kk[l], K4 = k4[l];
  const float* w = wptr[l];
  float* Wo = ws + woff[l] + m * K4;
  if (l == 0) {
    // layer 0 is depthwise-first: W[o][c*3+r], cout=19, cin(dw)=15
    for (int k = tid; k < 16; k += 128) {
      float v = 0.f;
      if (m < 19 && k < 15) { int c = k / 3, r = k % 3; v = w[(m * 5 + c) * 3 + r]; }
      Wo[k] = v;
    }
    return;
  }
  const int o = m / 3, r = m % 3;
  const int cout = coutt[l];
  const int cf = cinf[l], ch = chin_[l];
  const int itab[6] = {0, 0, 0, 1, 1, 2};
  const int jtab[6] = {0, 1, 2, 1, 2, 2};
  for (int k = tid; k < K4; k += 128) {
    float v = 0.f;
    if (o < cout && k < K) {
      if (k < ch) {
        v = w[(o * cf + k) * 3 + r];
      } else {
        int cc = k - ch;
        int mm = cc / 6, uu = cc % 6;
        int i = itab[uu], j = jtab[uu];
        v = w[(o * cf + ch + mm * 9 + i * 3 + j) * 3 + r];
        if (i != j) v += w[(o * cf + ch + mm * 9 + j * 3 + i) * 3 + r];
      }
    }
    Wo[k] = v;
  }
}

// ---------------- input channel sums (for the skip linear term) ----------------
__global__ __launch_bounds__(256) void insum_kernel(const float* __restrict__ x,
                                                    float* __restrict__ insum) {
  const int g = blockIdx.x * 256 + threadIdx.x;  // 81920 float4
  float4 v = ((const float4*)x)[g];
  float s = v.x + v.y + v.z + v.w;
  s = wred(s);
  if ((threadIdx.x & 63) == 0) atomicAdd(&insum[g >> 13], s);
}

// ---------------- layer 0: stride-2 depthwise (5 ch, 32^3 -> 16^3, 3 radial) ----------------
__global__ __launch_bounds__(256) void dw0_kernel(const float* __restrict__ x,
                                                  const float* __restrict__ basg,
                                                  float* __restrict__ z0) {
  const int g = blockIdx.x * 256 + threadIdx.x;  // 40960
  const int p = g & 4095;
  const int c = (g >> 12) % 5;
  const int b = g / (5 * 4096);
  const int X = p & 15, Y = (p >> 4) & 15, Z = p >> 8;
  const float* xp = x + (((size_t)(b * 5 + c)) << 15);
  float a0 = 0.f, a1 = 0.f, a2 = 0.f;
  for (int tz = 0; tz < 7; ++tz) {
    const int iz = 2 * Z + tz - 3;
    if ((unsigned)iz >= 32u) continue;
    for (int ty = 0; ty < 7; ++ty) {
      const int iy = 2 * Y + ty - 3;
      if ((unsigned)iy >= 32u) continue;
      const float* bb = &basg[(tz * 7 + ty) * 24];
      const float* row = xp + (iz << 10) + (iy << 5);
      #pragma unroll
      for (int tx = 0; tx < 7; ++tx) {
        const int ix = 2 * X + tx - 3;
        float v = ((unsigned)ix < 32u) ? row[ix] : 0.f;
        a0 = fmaf(bb[tx], v, a0);
        a1 = fmaf(bb[8 + tx], v, a1);
        a2 = fmaf(bb[16 + tx], v, a2);
      }
    }
  }
  const size_t base = (((size_t)(b * 15 + c * 3)) << 12) + p;
  z0[base] = a0;
  z0[base + 4096] = a1;
  z0[base + 8192] = a2;
}

// ---------------- GEMM: out[b,m,p] = sum_k W[m,k] * in[b,k,p]  (+ optional per-ch sumsq) ----
// W rows padded to K4, staged in LDS; each thread: 4 spatial (float4) x 8 channels
template <int K>
__global__ __launch_bounds__(256) void gemm_kernel(
    const float* __restrict__ in, const float* __restrict__ W,
    float* __restrict__ out, int Mreal, float* __restrict__ chsum) {
  constexpr int K4 = (K + 3) & ~3;
  __shared__ float Wl[8 * K4];
  const int b = blockIdx.z;
  const int m0 = blockIdx.y * 8;
  const int p0 = blockIdx.x * 1024 + threadIdx.x * 4;
  for (int i = threadIdx.x; i < 8 * K4; i += 256) Wl[i] = W[m0 * K4 + i];
  __syncthreads();
  const float* ip = in + (((size_t)b * K) << 12) + p0;
  float4 acc[8];
  #pragma unroll
  for (int j = 0; j < 8; ++j) acc[j] = make_float4(0.f, 0.f, 0.f, 0.f);
  int k = 0;
  for (; k + 4 <= K; k += 4) {
    const float4 v0 = *(const float4*)&ip[(size_t)(k + 0) << 12];
    const float4 v1 = *(const float4*)&ip[(size_t)(k + 1) << 12];
    const float4 v2 = *(const float4*)&ip[(size_t)(k + 2) << 12];
    const float4 v3 = *(const float4*)&ip[(size_t)(k + 3) << 12];
    #pragma unroll
    for (int j = 0; j < 8; ++j) {
      const float4 wv = *(const float4*)&Wl[j * K4 + k];
      acc[j].x = fmaf(wv.x, v0.x, acc[j].x); acc[j].y = fmaf(wv.x, v0.y, acc[j].y);
      acc[j].z = fmaf(wv.x, v0.z, acc[j].z); acc[j].w = fmaf(wv.x, v0.w, acc[j].w);
      acc[j].x = fmaf(wv.y, v1.x, acc[j].x); acc[j].y = fmaf(wv.y, v1.y, acc[j].y);
      acc[j].z = fmaf(wv.y, v1.z, acc[j].z); acc[j].w = fmaf(wv.y, v1.w, acc[j].w);
      acc[j].x = fmaf(wv.z, v2.x, acc[j].x); acc[j].y = fmaf(wv.z, v2.y, acc[j].y);
      acc[j].z = fmaf(wv.z, v2.z, acc[j].z); acc[j].w = fmaf(wv.z, v2.w, acc[j].w);
      acc[j].x = fmaf(wv.w, v3.x, acc[j].x); acc[j].y = fmaf(wv.w, v3.y, acc[j].y);
      acc[j].z = fmaf(wv.w, v3.z, acc[j].z); acc[j].w = fmaf(wv.w, v3.w, acc[j].w);
    }
  }
  for (; k < K; ++k) {
    const float4 v = *(const float4*)&ip[(size_t)k << 12];
    #pragma unroll
    for (int j = 0; j < 8; ++j) {
      const float w = Wl[j * K4 + k];
      acc[j].x = fmaf(w, v.x, acc[j].x); acc[j].y = fmaf(w, v.y, acc[j].y);
      acc[j].z = fmaf(w, v.z, acc[j].z); acc[j].w = fmaf(w, v.w, acc[j].w);
    }
  }
  #pragma unroll
  for (int j = 0; j < 8; ++j) {
    const int m = m0 + j;
    if (m < Mreal) *(float4*)&out[(((size_t)(b * Mreal + m)) << 12) + p0] = acc[j];
  }
  if (chsum) {
    #pragma unroll
    for (int j = 0; j < 8; ++j) {
      float s = acc[j].x * acc[j].x + acc[j].y * acc[j].y +
                acc[j].z * acc[j].z + acc[j].w * acc[j].w;
      s = wred(s);
      if ((threadIdx.x & 63) == 0) atomicAdd(&chsum[m0 + j], s);
    }
  }
}

// ---------------- depthwise-last: y[b,o,p] = sum_r basis_r (x) u[b,o*3+r,p] ----------------
// Block = (o, z-slab of 4, y-half of 8); 128 threads = (bx:4, yy:8, zz:4), 4 x-outputs each.
// LDS halo [3ch][10dz][14dy][32x] fp32, 16B-group parity swizzle g^=(dy&1)<<2:
// 8 consecutive lanes (2 dy-parities x 4 bx) hit 8 distinct 16B groups -> conflict-free b128.
__global__ __launch_bounds__(128) void dwB_kernel(
    const float* __restrict__ u, const float* __restrict__ basg,
    float* __restrict__ y, float* __restrict__ chsum, int cout) {
  __shared__ float lin[13440];  // 420 rows x 32 words = 52.5 KB
  const int b = blockIdx.y;
  const int o = blockIdx.x >> 3;
  const int rem = blockIdx.x & 7;
  const int zs = rem >> 1, yh = rem & 1;
  const int z0 = zs * 4, y0 = yh * 8;
  const int tid = threadIdx.x;
  const float* ubase = u + (((size_t)(b * 3 * cout + o * 3)) << 12);
  // fill: 420 rows x 8 groups; groups 1..4 hold the 16 valid x floats, rest zero
  for (int i = tid; i < 3360; i += 128) {
    const int g = i & 7;
    const int row = i >> 3;            // ch*140 + dz*14 + dy
    const int ch = row / 140;
    const int rr = row - ch * 140;
    const int dz = rr / 14;
    const int dy = rr - dz * 14;
    const int gz = z0 + dz - 3, gy = y0 + dy - 3;
    float4 v = make_float4(0.f, 0.f, 0.f, 0.f);
    if (g >= 1 && g <= 4 && (unsigned)gz < 16u && (unsigned)gy < 16u)
      v = *(const float4*)&ubase[(ch << 12) + (gz << 8) + (gy << 4) + ((g - 1) << 2)];
    const int sw = (dy & 1) << 2;
    *(float4*)&lin[row * 32 + ((g ^ sw) << 2)] = v;
  }
  __syncthreads();
  const int bx = tid & 3, yy = (tid >> 2) & 7, zz = tid >> 5;
  float acc[4] = {0.f, 0.f, 0.f, 0.f};
  #pragma unroll 1
  for (int tz = 0; tz < 7; ++tz) {
    #pragma unroll 1
    for (int ty = 0; ty < 7; ++ty) {
      const int dy = yy + ty;
      const int sw = (dy & 1) << 2;
      const int r0 = ((zz + tz) * 14 + dy) * 32;  // ch0 base; ch stride = 4480 words
      const int i0 = r0 + (((bx + 0) ^ sw) << 2);
      const int i1 = r0 + (((bx + 1) ^ sw) << 2);
      const int i2w = r0 + (((bx + 2) ^ sw) << 2);
      float4 a0 = *(const float4*)&lin[i0];
      float4 a1 = *(const float4*)&lin[i1];
      float4 a2 = *(const float4*)&lin[i2w];
      float4 b0 = *(const float4*)&lin[i0 + 4480];
      float4 b1 = *(const float4*)&lin[i1 + 4480];
      float4 b2 = *(const float4*)&lin[i2w + 4480];
      float4 c0 = *(const float4*)&lin[i0 + 8960];
      float4 c1 = *(const float4*)&lin[i1 + 8960];
      float4 c2 = *(const float4*)&lin[i2w + 8960];
      const float* bb = &basg[(tz * 7 + ty) * 24];
      const float va[12] = {a0.x,a0.y,a0.z,a0.w,a1.x,a1.y,a1.z,a1.w,a2.x,a2.y,a2.z,a2.w};
      const float vb[12] = {b0.x,b0.y,b0.z,b0.w,b1.x,b1.y,b1.z,b1.w,b2.x,b2.y,b2.z,b2.w};
      const float vc[12] = {c0.x,c0.y,c0.z,c0.w,c1.x,c1.y,c1.z,c1.w,c2.x,c2.y,c2.z,c2.w};
      #pragma unroll
      for (int tx = 0; tx < 7; ++tx) {
        const float w0 = bb[tx], w1 = bb[8 + tx], w2 = bb[16 + tx];
        #pragma unroll
        for (int i2 = 0; i2 < 4; ++i2) {
          acc[i2] = fmaf(w0, va[i2 + tx + 1], acc[i2]);
          acc[i2] = fmaf(w1, vb[i2 + tx + 1], acc[i2]);
          acc[i2] = fmaf(w2, vc[i2 + tx + 1], acc[i2]);
        }
      }
    }
  }
  const int p = ((z0 + zz) << 8) + ((y0 + yy) << 4) + bx * 4;
  float4 outv = {acc[0], acc[1], acc[2], acc[3]};
  *(float4*)&y[(((size_t)(b * cout + o)) << 12) + p] = outv;
  if (chsum) {
    float s = acc[0]*acc[0] + acc[1]*acc[1] + acc[2]*acc[2] + acc[3]*acc[3];
    s = wred(s);
    if ((tid & 63) == 0) atomicAdd(&chsum[o], s);
  }
}

// ---------------- norm + bias/relu + compressed TensorProduct -> next xcat ----------------
template <int COUT, int N1, int N3>
__global__ __launch_bounds__(64) void post_kernel(
    const float* __restrict__ y, const float* __restrict__ chsum,
    const float* __restrict__ bias, float* __restrict__ xout) {
  constexpr int N5 = (COUT - N1 - 3 * N3) / 5;
  constexpr int CO = COUT + 6 * N3;
  const int b = blockIdx.y;
  const int p = blockIdx.x * 64 + threadIdx.x;
  const float* yp = y + (((size_t)b * COUT) << 12) + p;
  float* xp = xout + (((size_t)b * CO) << 12) + p;
  const float inv = 1.f / 8192.f;
  float vals[COUT];
  #pragma unroll
  for (int c = 0; c < N1; ++c) {
    const float f = 1.f / sqrtf(chsum[c] * inv + 1e-5f);
    const float v = yp[(size_t)c << 12] * f + bias[c];
    vals[c] = v > 0.f ? v : 0.f;
  }
  #pragma unroll
  for (int m = 0; m < N3; ++m) {
    const int c0 = N1 + 3 * m;
    const float f = 1.f / sqrtf((chsum[c0] + chsum[c0 + 1] + chsum[c0 + 2]) * inv + 1e-5f);
    vals[c0]     = yp[(size_t)c0 << 12] * f;
    vals[c0 + 1] = yp[(size_t)(c0 + 1) << 12] * f;
    vals[c0 + 2] = yp[(size_t)(c0 + 2) << 12] * f;
  }
  #pragma unroll
  for (int m = 0; m < N5; ++m) {
    const int c0 = N1 + 3 * N3 + 5 * m;
    const float s5 = chsum[c0] + chsum[c0+1] + chsum[c0+2] + chsum[c0+3] + chsum[c0+4];
    const float f = 1.f / sqrtf(s5 * inv + 1e-5f);
    #pragma unroll
    for (int d = 0; d < 5; ++d) vals[c0 + d] = yp[(size_t)(c0 + d) << 12] * f;
  }
  #pragma unroll
  for (int c = 0; c < COUT; ++c) xp[(size_t)c << 12] = vals[c];
  #pragma unroll
  for (int m = 0; m < N3; ++m) {
    const float v0 = vals[N1 + 3*m], v1 = vals[N1 + 3*m + 1], v2 = vals[N1 + 3*m + 2];
    const float t[6] = {v0*v0, v0*v1, v0*v2, v1*v1, v1*v2, v2*v2};
    #pragma unroll
    for (int uu = 0; uu < 6; ++uu) xp[(size_t)(COUT + m * 6 + uu) << 12] = t[uu];
  }
}

// ---------------- final: spatial mean of y5 + input-sum linear term ----------------
__global__ __launch_bounds__(256) void final_kernel(
    const float* __restrict__ y5, const float* __restrict__ acc,
    const float* __restrict__ lin_w, const float* __restrict__ lin_b,
    const float* __restrict__ alpha, float* __restrict__ out) {
  const int b = blockIdx.x;
  const int tid = threadIdx.x;
  float s = 0.f;
  for (int i = tid; i < 4096; i += 256) s += y5[(b << 12) + i];
  s = wred(s);
  __shared__ float ls[4];
  if ((tid & 63) == 0) ls[tid >> 6] = s;
  __syncthreads();
  if (tid == 0) {
    const float t = ls[0] + ls[1] + ls[2] + ls[3];
    float res = t * (1.f / 4096.f) * alpha[0] * 0.1f;
    const float* insum = acc + 240;
    for (int c = 0; c < 5; ++c) res += insum[b * 5 + c] * lin_w[c];
    res += lin_b[0];
    out[b] = res;
  }
}

extern "C" void kernel_launch(void* const* d_in, const int* in_sizes, int n_in,
                              void* d_out, int out_size, void* d_ws, size_t ws_size,
                              hipStream_t stream) {
  const float* x  = (const float*)d_in[0];
  const float* w0 = (const float*)d_in[1];
  const float* w1 = (const float*)d_in[2];
  const float* w2 = (const float*)d_in[3];
  const float* w3 = (const float*)d_in[4];
  const float* w4 = (const float*)d_in[5];
  const float* w5 = (const float*)d_in[6];
  const float* b0 = (const float*)d_in[7];
  const float* b1 = (const float*)d_in[8];
  const float* b2 = (const float*)d_in[9];
  const float* b3 = (const float*)d_in[10];
  const float* b4 = (const float*)d_in[11];
  const float* lw = (const float*)d_in[12];
  const float* lb = (const float*)d_in[13];
  const float* al = (const float*)d_in[14];
  float* out = (float*)d_out;
  float* ws = (float*)d_ws;

  float* bas = ws + OFF_BAS;
  float* acc = ws + OFF_ACC;
  float* XA = ws + OFF_XA;
  float* XB = ws + OFF_XB;
  float* U  = ws + OFF_U;
  float* Y  = ws + OFF_Y;

  hipMemsetAsync(acc, 0, 256 * sizeof(float), stream);
  hipLaunchKernelGGL(prep_kernel, dim3(513), dim3(128), 0, stream, w0, w1, w2, w3, w4, w5, ws);
  hipLaunchKernelGGL(insum_kernel, dim3(320), dim3(256), 0, stream, x, acc + 240);

  // L0: depthwise-first (stride 2), then GEMM (+sumsq), then norm/relu + TP -> XA (37 ch)
  hipLaunchKernelGGL(dw0_kernel, dim3(160), dim3(256), 0, stream, x, bas, U);
  hipLaunchKernelGGL(gemm_kernel<15>, dim3(4, 3, 2), dim3(256), 0, stream,
                     U, ws + WOFF0, Y, 19, acc);
  hipLaunchKernelGGL((post_kernel<19, 10, 3>), dim3(64, 2), dim3(64), 0, stream, Y, acc, b0, XA);

  // L1: GEMM-first (K=37 -> 72 u-ch), depthwise(+sumsq), post -> XB (42 ch)
  hipLaunchKernelGGL(gemm_kernel<37>, dim3(4, 9, 2), dim3(256), 0, stream,
                     XA, ws + WOFF1, U, 72, (float*)nullptr);
  hipLaunchKernelGGL(dwB_kernel, dim3(192, 2), dim3(128), 0, stream, U, bas, Y, acc + 48, 24);
  hipLaunchKernelGGL((post_kernel<24, 10, 3>), dim3(64, 2), dim3(64), 0, stream, Y, acc + 48, b1, XB);

  // L2: K=42 -> 135 u-ch, cout=45 -> XA (93 ch)
  hipLaunchKernelGGL(gemm_kernel<42>, dim3(4, 17, 2), dim3(256), 0, stream,
                     XB, ws + WOFF2, U, 135, (float*)nullptr);
  hipLaunchKernelGGL(dwB_kernel, dim3(360, 2), dim3(128), 0, stream, U, bas, Y, acc + 96, 45);
  hipLaunchKernelGGL((post_kernel<45, 16, 8>), dim3(64, 2), dim3(64), 0, stream, Y, acc + 96, b2, XA);

  // L3
  hipLaunchKernelGGL(gemm_kernel<93>, dim3(4, 17, 2), dim3(256), 0, stream,
                     XA, ws + WOFF3, U, 135, (float*)nullptr);
  hipLaunchKernelGGL(dwB_kernel, dim3(360, 2), dim3(128), 0, stream, U, bas, Y, acc + 144, 45);
  hipLaunchKernelGGL((post_kernel<45, 16, 8>), dim3(64, 2), dim3(64), 0, stream, Y, acc + 144, b3, XB);

  // L4
  hipLaunchKernelGGL(gemm_kernel<93>, dim3(4, 17, 2), dim3(256), 0, stream,
                     XB, ws + WOFF4, U, 135, (float*)nullptr);
  hipLaunchKernelGGL(dwB_kernel, dim3(360, 2), dim3(128), 0, stream, U, bas, Y, acc + 192, 45);
  hipLaunchKernelGGL((post_kernel<45, 16, 8>), dim3(64, 2), dim3(64), 0, stream, Y, acc + 192, b4, XA);

  // L5: cout=1, no norm
  hipLaunchKernelGGL(gemm_kernel<93>, dim3(4, 1, 2), dim3(256), 0, stream,
                     XA, ws + WOFF5, U, 3, (float*)nullptr);
  hipLaunchKernelGGL(dwB_kernel, dim3(8, 2), dim3(128), 0, stream, U, bas, Y, (float*)nullptr, 1);

  hipLaunchKernelGGL(final_kernel, dim3(2), dim3(256), 0, stream, Y, acc, lw, lb, al, out);
}